// Round 8
// baseline (5035.030 us; speedup 1.0000x reference)
//
#include <hip/hip_runtime.h>

typedef unsigned long long u64;

#define SEG_N     8192
#define NSEG      2
#define M_PER_SEG 2048
#define M_TOTAL   4096
#define CFEAT     64
#define COUT      128
#define NSAMPLE   16

#define FPS_WGS_PER_SEG 16
#define FPS_THREADS     512
#define FPS_WAVES       8
#define SLOT_STRIDE     16    // u64s per (parity,seg) row = 128B line

// d_out layout (floats): new_xyz | new_feat | new_offset | new_vel
#define OUT_XYZ   0
#define OUT_FEAT  12288      // 4096*3
#define OUT_OFF   536576     // + 4096*128
#define OUT_VEL   536578     // + 2

// d_ws layout (bytes)
#define WS_CAND 0            // u64 cand[2][2][16]  (parity, seg, wg) = 512 B
#define WS_FPS  512          // int fps_idx[2][2048]
#define WS_KNN  16896        // int knn[4096][16]

#define AG  __HIP_MEMORY_SCOPE_AGENT
#define RLX __ATOMIC_RELAXED

#define REP16(M) M(0) M(1) M(2) M(3) M(4) M(5) M(6) M(7) \
                 M(8) M(9) M(10) M(11) M(12) M(13) M(14) M(15)
#define REP16_EO(E,O) E(0) O(1) E(2) O(3) E(4) O(5) E(6) O(7) \
                      E(8) O(9) E(10) O(11) E(12) O(13) E(14) O(15)

// ---------------------------------------------------------------------------
// FPS, register-resident via NAMED SCALARS (no allocas -> nothing can spill):
// 16 WGs/segment x 512 threads; each thread owns one point (3 scalars + 16
// named float4 = 67 floats) and the current query q in the same form.
// SROA runs before unrolling, so float p[67] indexed by a loop variable goes
// to scratch (R6/R7: VGPR_Count=52); named variables cannot be indexed and
// must be register-allocated (~165 VGPR, fits the 256 cap of (512,2)).
// Per step: 67-dim dist emitted in ascending-dim order with 8 named
// accumulators mapped exactly as numpy's pairwise r[d&7] (k-even float4 ->
// r3..r6, k-odd -> r7,r0,r1,r2), mul-then-add under fp contract(off);
// fmin; 64-lane shfl argmax; 8-wave LDS funnel; barrier; wave 0 merges,
// publishes ONE step-tagged u64 per WG (RELAXED agent atomic, parity
// double-buffered), polls the segment's 16 slots (one 128B line, lane<16),
// butterfly-reduces, broadcasts winner via LDS; barrier; q reload.
// ---------------------------------------------------------------------------
__global__ __launch_bounds__(FPS_THREADS, 2)
void fps_kernel(const float* __restrict__ xyz, const float* __restrict__ feat,
                u64* __restrict__ cand, int* __restrict__ fps_idx)
{
#pragma clang fp contract(off)
  __shared__ u64 wslot[FPS_WAVES];
  __shared__ int qidx_sh;

  const int tid  = threadIdx.x;
  const int lane = tid & 63;
  const int wv   = tid >> 6;
  const int s    = blockIdx.x >> 4;
  const int wg   = blockIdx.x & 15;
  const int pl   = wg * FPS_THREADS + tid;        // segment-local point id
  const size_t gr = (size_t)(s * SEG_N + pl);     // global row

  // ---- my point: named registers (one-time gather) ----
  float px, py, pz;
#define DECLP(k) float4 pf##k;
  REP16(DECLP)
  px = xyz[gr*3+0]; py = xyz[gr*3+1]; pz = xyz[gr*3+2];
  {
    const float4* fr = (const float4*)(feat + gr * CFEAT);
#define LOADP(k) pf##k = fr[k];
    REP16(LOADP)
  }

  // ---- query q: named registers, reloaded every step ----
  float qx, qy, qz;
#define DECLQ(k) float4 qf##k;
  REP16(DECLQ)
#define LOADQ1(k) qf##k = frq[k];
#define LOAD_Q(qb) { \
    qx = xyz[(qb)*3+0]; qy = xyz[(qb)*3+1]; qz = xyz[(qb)*3+2]; \
    const float4* frq = (const float4*)(feat + (qb) * CFEAT); \
    REP16(LOADQ1) }

  LOAD_Q((size_t)(s * SEG_N))
  if (tid == 0 && wg == 0) fps_idx[s * M_PER_SEG] = 0;

  float D = 1e10f;

  for (int t = 1; t < M_PER_SEG; ++t) {
    // numpy-pairwise-exact: ascending d, acc (d&7), mul then add (no fma)
    float r0=0.f, r1=0.f, r2=0.f, r3=0.f, r4=0.f, r5=0.f, r6=0.f, r7=0.f;
    {
      float tt;
      tt = px - qx; r0 += tt*tt;   // d=0
      tt = py - qy; r1 += tt*tt;   // d=1
      tt = pz - qz; r2 += tt*tt;   // d=2
    }
#define DE(k) { float t0 = pf##k.x - qf##k.x; r3 += t0*t0; \
                float t1 = pf##k.y - qf##k.y; r4 += t1*t1; \
                float t2 = pf##k.z - qf##k.z; r5 += t2*t2; \
                float t3 = pf##k.w - qf##k.w; r6 += t3*t3; }
#define DO(k) { float t0 = pf##k.x - qf##k.x; r7 += t0*t0; \
                float t1 = pf##k.y - qf##k.y; r0 += t1*t1; \
                float t2 = pf##k.z - qf##k.z; r1 += t2*t2; \
                float t3 = pf##k.w - qf##k.w; r2 += t3*t3; }
    REP16_EO(DE, DO)
    float a = ((r0+r1)+(r2+r3)) + ((r4+r5)+(r6+r7));
    D = fminf(D, a);

    // 64-lane argmax, ties -> lowest index
    float bd = D; int bi = pl;
    #pragma unroll
    for (int off = 32; off >= 1; off >>= 1) {
      float od = __shfl_xor(bd, off);
      int   oi = __shfl_xor(bi, off);
      if (od > bd || (od == bd && oi < bi)) { bd = od; bi = oi; }
    }
    if (lane == 0)
      wslot[wv] = ((u64)__float_as_uint(bd) << 13) | (u64)(unsigned)(8191 - bi);
    __syncthreads();                               // funnel ready

    if (wv == 0) {
      u64 w = (lane < FPS_WAVES) ? wslot[lane] : 0ULL;
      #pragma unroll
      for (int off = 4; off >= 1; off >>= 1) {
        u64 o = __shfl_xor(w, off, 8);
        if (o > w) w = o;
      }
      u64* base = &cand[(((unsigned)t & 1u) * NSEG + s) * SLOT_STRIDE];
      if (lane == 0)
        __hip_atomic_store(&base[wg], ((u64)(unsigned)t << 45) | w, RLX, AG);

      // poll the segment's 16 WG-slots (one 128B line, one per lane<16)
      u64 v = 0;
      if (lane < FPS_WGS_PER_SEG) {
        v = __hip_atomic_load(&base[lane], RLX, AG);
        while ((unsigned)(v >> 45) != (unsigned)t) {
          __builtin_amdgcn_s_sleep(1);
          v = __hip_atomic_load(&base[lane], RLX, AG);
        }
      }
      // 16-wide butterfly max (tagged winners dominate 0-filled lanes)
      #pragma unroll
      for (int off = 8; off >= 1; off >>= 1) {
        u64 o = __shfl_xor(v, off, 16);
        if (o > v) v = o;
      }
      int qi = 8191 - (int)(v & 0x1FFFu);
      if (lane == 0) {
        qidx_sh = qi;
        if (wg == 0) fps_idx[s * M_PER_SEG + t] = qi;
      }
    }
    __syncthreads();                               // winner broadcast

    // reload q's 67 coords (uniform row, L2-hot) into named registers
    LOAD_Q((size_t)(s * SEG_N + qidx_sh))
  }
}

// ---------------------------------------------------------------------------
__global__ void gather_kernel(const float* __restrict__ xyz, const float* __restrict__ vel,
                              const int* __restrict__ fps_idx, float* __restrict__ out)
{
  int i = blockIdx.x * 256 + threadIdx.x;
  if (i >= M_TOTAL) return;
  int s = i >> 11, r = i & 2047;
  int g = s * SEG_N + (fps_idx[s * M_PER_SEG + r] & 8191);
  out[OUT_XYZ + i*3 + 0] = xyz[(size_t)g*3 + 0];
  out[OUT_XYZ + i*3 + 1] = xyz[(size_t)g*3 + 1];
  out[OUT_XYZ + i*3 + 2] = xyz[(size_t)g*3 + 2];
  out[OUT_VEL + i*3 + 0] = vel[(size_t)g*3 + 0];
  out[OUT_VEL + i*3 + 1] = vel[(size_t)g*3 + 1];
  out[OUT_VEL + i*3 + 2] = vel[(size_t)g*3 + 2];
  if (i == 0) { out[OUT_OFF] = 2048.0f; out[OUT_OFF + 1] = 4096.0f; }
}

// ---------------------------------------------------------------------------
// kNN: 16 queries/WG, 16 scanner-threads/query. Phase 1: per-thread sorted
// top-16 (med3 chain) over stride-16 candidates from LDS tiles; 16-way merge
// -> exact global 16th-smallest T. Phase 2: rescan, collect d2 <= T*(1+eps),
// pick 16 by (d2, idx).
// ---------------------------------------------------------------------------
#define KNN_TILE 1024
__global__ __launch_bounds__(256)
void knn_kernel(const float* __restrict__ xyz, const float* __restrict__ out,
                int* __restrict__ knn)
{
  __shared__ float px[KNN_TILE], py[KNN_TILE], pz[KNN_TILE];
  __shared__ float ldK[16][16][16];
  __shared__ float Tq[16];
  __shared__ float dbuf[16][24];
  __shared__ int   cbuf[16][24];
  __shared__ int   cnt[16];

  const int tid = threadIdx.x;
  const int ql = tid >> 4, j = tid & 15;
  const int qg = blockIdx.x * 16 + ql;
  const int s  = qg >> 11;
  const float qx = out[OUT_XYZ + qg*3 + 0];
  const float qy = out[OUT_XYZ + qg*3 + 1];
  const float qz = out[OUT_XYZ + qg*3 + 2];
  const float sq = qx*qx + qy*qy + qz*qz;

  float K[16];
  #pragma unroll
  for (int r = 0; r < 16; ++r) K[r] = 3.4e38f;

  for (int tile = 0; tile < SEG_N / KNN_TILE; ++tile) {
    __syncthreads();
    for (int u = tid; u < KNN_TILE; u += 256) {
      size_t g = (size_t)(s * SEG_N + tile * KNN_TILE + u);
      px[u] = xyz[g*3+0]; py[u] = xyz[g*3+1]; pz[u] = xyz[g*3+2];
    }
    __syncthreads();
    #pragma unroll 4
    for (int i = 0; i < KNN_TILE / 16; ++i) {
      int c = i * 16 + j;
      float x = px[c], y = py[c], z = pz[c];
      float sp  = x*x + y*y + z*z;
      float dot = qx*x + qy*y + qz*z;
      float d2  = (sq + sp) - 2.0f * dot;
      #pragma unroll
      for (int r = 15; r >= 1; --r)
        K[r] = fminf(fmaxf(d2, K[r-1]), K[r]);
      K[0] = fminf(K[0], d2);
    }
  }
  #pragma unroll
  for (int r = 0; r < 16; ++r) ldK[ql][j][r] = K[r];
  __syncthreads();

  {
    int head = 0;
    float T = 3.4e38f;
    for (int r = 0; r < 16; ++r) {
      float val = (head < 16) ? ldK[ql][j][head] : 3.4e38f;
      float mv = val; int ml = j;
      #pragma unroll
      for (int off = 8; off >= 1; off >>= 1) {
        float ov = __shfl_xor(mv, off, 16);
        int   ol = __shfl_xor(ml, off, 16);
        if (ov < mv || (ov == mv && ol < ml)) { mv = ov; ml = ol; }
      }
      if (j == ml) head++;
      T = mv;
    }
    if (j == 0) { Tq[ql] = T; cnt[ql] = 0; }
  }
  __syncthreads();
  const float T  = Tq[ql];
  const float Tm = T + fabsf(T) * 1e-6f + 1e-30f;

  for (int tile = 0; tile < SEG_N / KNN_TILE; ++tile) {
    __syncthreads();
    for (int u = tid; u < KNN_TILE; u += 256) {
      size_t g = (size_t)(s * SEG_N + tile * KNN_TILE + u);
      px[u] = xyz[g*3+0]; py[u] = xyz[g*3+1]; pz[u] = xyz[g*3+2];
    }
    __syncthreads();
    for (int i = 0; i < KNN_TILE / 16; ++i) {
      int c = i * 16 + j;
      float x = px[c], y = py[c], z = pz[c];
      float sp  = x*x + y*y + z*z;
      float dot = qx*x + qy*y + qz*z;
      float d2  = (sq + sp) - 2.0f * dot;
      if (d2 <= Tm) {
        int pos = atomicAdd(&cnt[ql], 1);
        if (pos < 24) { dbuf[ql][pos] = d2; cbuf[ql][pos] = tile * KNN_TILE + c; }
      }
    }
  }
  __syncthreads();

  if (j == 0) {
    int n = cnt[ql]; if (n > 24) n = 24;
    for (int r = 0; r < NSAMPLE; ++r) {
      float bv = 3.4e38f; int bc = 0, bp = -1;
      for (int e = 0; e < n; ++e) {
        float dv = dbuf[ql][e]; int cc = cbuf[ql][e];
        if (dv < bv || (dv == bv && cc < bc)) { bv = dv; bc = cc; bp = e; }
      }
      if (bp >= 0) dbuf[ql][bp] = 3.4e38f;
      knn[qg * NSAMPLE + r] = bc;
    }
  }
}

// ---------------------------------------------------------------------------
// Gather 16 neighbor feature rows, Linear(64->128) no bias, ReLU, max over k.
// ---------------------------------------------------------------------------
__global__ __launch_bounds__(128)
void gemm_kernel(const float* __restrict__ feat, const float* __restrict__ W,
                 const int* __restrict__ knn, float* __restrict__ out)
{
  __shared__ __align__(16) float f[NSAMPLE][CFEAT];
  __shared__ int kid[NSAMPLE];
  const int tid = threadIdx.x;
  const int q = blockIdx.x;
  const int s = q >> 11;
  if (tid < NSAMPLE) kid[tid] = knn[q * NSAMPLE + tid] & 8191;
  __syncthreads();
  for (int e = tid; e < NSAMPLE * CFEAT; e += 128) {
    int k = e >> 6, c = e & 63;
    f[k][c] = feat[(size_t)(s * SEG_N + kid[k]) * CFEAT + c];
  }
  float4 w[16];
  const float4* Wrow = (const float4*)(W + (size_t)tid * CFEAT);
  #pragma unroll
  for (int c4 = 0; c4 < 16; ++c4) w[c4] = Wrow[c4];
  __syncthreads();

  float m = -3.4e38f;
  #pragma unroll
  for (int k = 0; k < NSAMPLE; ++k) {
    float acc = 0.f;
    const float4* frow = (const float4*)&f[k][0];
    #pragma unroll
    for (int c4 = 0; c4 < 16; ++c4) {
      float4 fv = frow[c4];
      acc += fv.x * w[c4].x + fv.y * w[c4].y + fv.z * w[c4].z + fv.w * w[c4].w;
    }
    m = fmaxf(m, acc);
  }
  out[OUT_FEAT + (size_t)q * COUT + tid] = fmaxf(m, 0.f);
}

// ---------------------------------------------------------------------------
extern "C" void kernel_launch(void* const* d_in, const int* in_sizes, int n_in,
                              void* d_out, int out_size, void* d_ws, size_t ws_size,
                              hipStream_t stream)
{
  const float* xyz  = (const float*)d_in[0];
  const float* feat = (const float*)d_in[1];
  // d_in[2] = offset (segment sizes fixed by the problem)
  const float* vel  = (const float*)d_in[3];
  const float* W    = (const float*)d_in[4];
  float* out = (float*)d_out;
  char*  ws  = (char*)d_ws;
  u64* cand    = (u64*)(ws + WS_CAND);
  int* fps_idx = (int*)(ws + WS_FPS);
  int* knn     = (int*)(ws + WS_KNN);

  // step tags repeat across graph replays -> slots must start clean
  hipMemsetAsync(cand, 0, 512, stream);

  fps_kernel<<<NSEG * FPS_WGS_PER_SEG, FPS_THREADS, 0, stream>>>(
      xyz, feat, cand, fps_idx);
  gather_kernel<<<M_TOTAL / 256, 256, 0, stream>>>(xyz, vel, fps_idx, out);
  knn_kernel<<<M_TOTAL / 16, 256, 0, stream>>>(xyz, out, knn);
  gemm_kernel<<<M_TOTAL, 128, 0, stream>>>(feat, W, knn, out);
}

// Round 9
// 5025.070 us; speedup vs baseline: 1.0020x; 1.0020x over previous
//
#include <hip/hip_runtime.h>

typedef unsigned long long u64;

#define SEG_N     8192
#define NSEG      2
#define M_PER_SEG 2048
#define M_TOTAL   4096
#define CFEAT     64
#define COUT      128
#define NSAMPLE   16

#define FPS_WGS_PER_SEG 16
#define FPS_THREADS     512
#define FPS_WAVES       8
#define SLOT_STRIDE     16    // u64s per (parity,seg) row = 128B line

// d_out layout (floats): new_xyz | new_feat | new_offset | new_vel
#define OUT_XYZ   0
#define OUT_FEAT  12288      // 4096*3
#define OUT_OFF   536576     // + 4096*128
#define OUT_VEL   536578     // + 2

// d_ws layout (bytes)
#define WS_CAND 0            // u64 cand[2][2][16]  (parity, seg, wg) = 512 B
#define WS_FPS  512          // int fps_idx[2][2048]
#define WS_KNN  16896        // int knn[4096][16]

#define AG  __HIP_MEMORY_SCOPE_AGENT
#define RLX __ATOMIC_RELAXED

#define REP16(M) M(0) M(1) M(2) M(3) M(4) M(5) M(6) M(7) \
                 M(8) M(9) M(10) M(11) M(12) M(13) M(14) M(15)
#define REP16_EO(E,O) E(0) O(1) E(2) O(3) E(4) O(5) E(6) O(7) \
                      E(8) O(9) E(10) O(11) E(12) O(13) E(14) O(15)

// ---------------------------------------------------------------------------
// FPS, register-resident. R6/R7/R8 all showed VGPR_Count=52: the register
// allocator targets the MAX of the waves-per-eu range (launch_bounds' 2nd arg
// only sets the MIN), budgets 64 VGPRs, and spills the 134 live floats to
// scratch. amdgpu_waves_per_eu(2,2) clamps min AND max to 2 waves/EU ->
// 256-VGPR budget -> the named-scalar point (3 + 16 float4) and query fit in
// registers with no spill. Grid = 32 WGs on 32 CUs (1 WG/CU = 2 waves/SIMD),
// so the clamp costs nothing.
// Per step: 67-dim dist emitted ascending-dim with 8 named accumulators
// mapped exactly as numpy's pairwise r[d&7] (k-even float4 -> r3..r6, k-odd
// -> r7,r0,r1,r2), mul-then-add under fp contract(off); fmin; 64-lane shfl
// argmax (ties->lowest idx); 8-wave LDS funnel; barrier; wave 0 merges,
// publishes ONE step-tagged u64 per WG (RELAXED agent atomic, parity
// double-buffered), polls the segment's 16 slots (one 128B line, lane<16),
// butterfly-reduces, broadcasts winner via LDS; barrier; uniform q reload.
// ---------------------------------------------------------------------------
__global__ __attribute__((amdgpu_waves_per_eu(2, 2)))
__launch_bounds__(FPS_THREADS)
void fps_kernel(const float* __restrict__ xyz, const float* __restrict__ feat,
                u64* __restrict__ cand, int* __restrict__ fps_idx)
{
#pragma clang fp contract(off)
  __shared__ u64 wslot[FPS_WAVES];
  __shared__ int qidx_sh;

  const int tid  = threadIdx.x;
  const int lane = tid & 63;
  const int wv   = tid >> 6;
  const int s    = blockIdx.x >> 4;
  const int wg   = blockIdx.x & 15;
  const int pl   = wg * FPS_THREADS + tid;        // segment-local point id
  const size_t gr = (size_t)(s * SEG_N + pl);     // global row

  // ---- my point: named registers (one-time gather) ----
  float px, py, pz;
#define DECLP(k) float4 pf##k;
  REP16(DECLP)
  px = xyz[gr*3+0]; py = xyz[gr*3+1]; pz = xyz[gr*3+2];
  {
    const float4* fr = (const float4*)(feat + gr * CFEAT);
#define LOADP(k) pf##k = fr[k];
    REP16(LOADP)
  }

  // ---- query q: named registers, reloaded every step ----
  float qx, qy, qz;
#define DECLQ(k) float4 qf##k;
  REP16(DECLQ)
#define LOADQ1(k) qf##k = frq[k];
#define LOAD_Q(qb) { \
    qx = xyz[(qb)*3+0]; qy = xyz[(qb)*3+1]; qz = xyz[(qb)*3+2]; \
    const float4* frq = (const float4*)(feat + (qb) * CFEAT); \
    REP16(LOADQ1) }

  LOAD_Q((size_t)(s * SEG_N))
  if (tid == 0 && wg == 0) fps_idx[s * M_PER_SEG] = 0;

  float D = 1e10f;

  for (int t = 1; t < M_PER_SEG; ++t) {
    // numpy-pairwise-exact: ascending d, acc (d&7), mul then add (no fma)
    float r0=0.f, r1=0.f, r2=0.f, r3=0.f, r4=0.f, r5=0.f, r6=0.f, r7=0.f;
    {
      float tt;
      tt = px - qx; r0 += tt*tt;   // d=0
      tt = py - qy; r1 += tt*tt;   // d=1
      tt = pz - qz; r2 += tt*tt;   // d=2
    }
#define DE(k) { float t0 = pf##k.x - qf##k.x; r3 += t0*t0; \
                float t1 = pf##k.y - qf##k.y; r4 += t1*t1; \
                float t2 = pf##k.z - qf##k.z; r5 += t2*t2; \
                float t3 = pf##k.w - qf##k.w; r6 += t3*t3; }
#define DO(k) { float t0 = pf##k.x - qf##k.x; r7 += t0*t0; \
                float t1 = pf##k.y - qf##k.y; r0 += t1*t1; \
                float t2 = pf##k.z - qf##k.z; r1 += t2*t2; \
                float t3 = pf##k.w - qf##k.w; r2 += t3*t3; }
    REP16_EO(DE, DO)
    float a = ((r0+r1)+(r2+r3)) + ((r4+r5)+(r6+r7));
    D = fminf(D, a);

    // 64-lane argmax, ties -> lowest index
    float bd = D; int bi = pl;
    #pragma unroll
    for (int off = 32; off >= 1; off >>= 1) {
      float od = __shfl_xor(bd, off);
      int   oi = __shfl_xor(bi, off);
      if (od > bd || (od == bd && oi < bi)) { bd = od; bi = oi; }
    }
    if (lane == 0)
      wslot[wv] = ((u64)__float_as_uint(bd) << 13) | (u64)(unsigned)(8191 - bi);
    __syncthreads();                               // funnel ready

    if (wv == 0) {
      u64 w = (lane < FPS_WAVES) ? wslot[lane] : 0ULL;
      #pragma unroll
      for (int off = 4; off >= 1; off >>= 1) {
        u64 o = __shfl_xor(w, off, 8);
        if (o > w) w = o;
      }
      u64* base = &cand[(((unsigned)t & 1u) * NSEG + s) * SLOT_STRIDE];
      if (lane == 0)
        __hip_atomic_store(&base[wg], ((u64)(unsigned)t << 45) | w, RLX, AG);

      // poll the segment's 16 WG-slots (one 128B line, one per lane<16)
      u64 v = 0;
      if (lane < FPS_WGS_PER_SEG) {
        v = __hip_atomic_load(&base[lane], RLX, AG);
        while ((unsigned)(v >> 45) != (unsigned)t) {
          __builtin_amdgcn_s_sleep(1);
          v = __hip_atomic_load(&base[lane], RLX, AG);
        }
      }
      // 16-wide butterfly max (tagged winners dominate 0-filled lanes)
      #pragma unroll
      for (int off = 8; off >= 1; off >>= 1) {
        u64 o = __shfl_xor(v, off, 16);
        if (o > v) v = o;
      }
      int qi = 8191 - (int)(v & 0x1FFFu);
      if (lane == 0) {
        qidx_sh = qi;
        if (wg == 0) fps_idx[s * M_PER_SEG + t] = qi;
      }
    }
    __syncthreads();                               // winner broadcast

    // reload q's 67 coords (uniform row, L2-hot) into named registers
    LOAD_Q((size_t)(s * SEG_N + qidx_sh))
  }
}

// ---------------------------------------------------------------------------
__global__ void gather_kernel(const float* __restrict__ xyz, const float* __restrict__ vel,
                              const int* __restrict__ fps_idx, float* __restrict__ out)
{
  int i = blockIdx.x * 256 + threadIdx.x;
  if (i >= M_TOTAL) return;
  int s = i >> 11, r = i & 2047;
  int g = s * SEG_N + (fps_idx[s * M_PER_SEG + r] & 8191);
  out[OUT_XYZ + i*3 + 0] = xyz[(size_t)g*3 + 0];
  out[OUT_XYZ + i*3 + 1] = xyz[(size_t)g*3 + 1];
  out[OUT_XYZ + i*3 + 2] = xyz[(size_t)g*3 + 2];
  out[OUT_VEL + i*3 + 0] = vel[(size_t)g*3 + 0];
  out[OUT_VEL + i*3 + 1] = vel[(size_t)g*3 + 1];
  out[OUT_VEL + i*3 + 2] = vel[(size_t)g*3 + 2];
  if (i == 0) { out[OUT_OFF] = 2048.0f; out[OUT_OFF + 1] = 4096.0f; }
}

// ---------------------------------------------------------------------------
// kNN: 16 queries/WG, 16 scanner-threads/query. Phase 1: per-thread sorted
// top-16 (med3 chain) over stride-16 candidates from LDS tiles; 16-way merge
// -> exact global 16th-smallest T. Phase 2: rescan, collect d2 <= T*(1+eps),
// pick 16 by (d2, idx).
// ---------------------------------------------------------------------------
#define KNN_TILE 1024
__global__ __launch_bounds__(256)
void knn_kernel(const float* __restrict__ xyz, const float* __restrict__ out,
                int* __restrict__ knn)
{
  __shared__ float px[KNN_TILE], py[KNN_TILE], pz[KNN_TILE];
  __shared__ float ldK[16][16][16];
  __shared__ float Tq[16];
  __shared__ float dbuf[16][24];
  __shared__ int   cbuf[16][24];
  __shared__ int   cnt[16];

  const int tid = threadIdx.x;
  const int ql = tid >> 4, j = tid & 15;
  const int qg = blockIdx.x * 16 + ql;
  const int s  = qg >> 11;
  const float qx = out[OUT_XYZ + qg*3 + 0];
  const float qy = out[OUT_XYZ + qg*3 + 1];
  const float qz = out[OUT_XYZ + qg*3 + 2];
  const float sq = qx*qx + qy*qy + qz*qz;

  float K[16];
  #pragma unroll
  for (int r = 0; r < 16; ++r) K[r] = 3.4e38f;

  for (int tile = 0; tile < SEG_N / KNN_TILE; ++tile) {
    __syncthreads();
    for (int u = tid; u < KNN_TILE; u += 256) {
      size_t g = (size_t)(s * SEG_N + tile * KNN_TILE + u);
      px[u] = xyz[g*3+0]; py[u] = xyz[g*3+1]; pz[u] = xyz[g*3+2];
    }
    __syncthreads();
    #pragma unroll 4
    for (int i = 0; i < KNN_TILE / 16; ++i) {
      int c = i * 16 + j;
      float x = px[c], y = py[c], z = pz[c];
      float sp  = x*x + y*y + z*z;
      float dot = qx*x + qy*y + qz*z;
      float d2  = (sq + sp) - 2.0f * dot;
      #pragma unroll
      for (int r = 15; r >= 1; --r)
        K[r] = fminf(fmaxf(d2, K[r-1]), K[r]);
      K[0] = fminf(K[0], d2);
    }
  }
  #pragma unroll
  for (int r = 0; r < 16; ++r) ldK[ql][j][r] = K[r];
  __syncthreads();

  {
    int head = 0;
    float T = 3.4e38f;
    for (int r = 0; r < 16; ++r) {
      float val = (head < 16) ? ldK[ql][j][head] : 3.4e38f;
      float mv = val; int ml = j;
      #pragma unroll
      for (int off = 8; off >= 1; off >>= 1) {
        float ov = __shfl_xor(mv, off, 16);
        int   ol = __shfl_xor(ml, off, 16);
        if (ov < mv || (ov == mv && ol < ml)) { mv = ov; ml = ol; }
      }
      if (j == ml) head++;
      T = mv;
    }
    if (j == 0) { Tq[ql] = T; cnt[ql] = 0; }
  }
  __syncthreads();
  const float T  = Tq[ql];
  const float Tm = T + fabsf(T) * 1e-6f + 1e-30f;

  for (int tile = 0; tile < SEG_N / KNN_TILE; ++tile) {
    __syncthreads();
    for (int u = tid; u < KNN_TILE; u += 256) {
      size_t g = (size_t)(s * SEG_N + tile * KNN_TILE + u);
      px[u] = xyz[g*3+0]; py[u] = xyz[g*3+1]; pz[u] = xyz[g*3+2];
    }
    __syncthreads();
    for (int i = 0; i < KNN_TILE / 16; ++i) {
      int c = i * 16 + j;
      float x = px[c], y = py[c], z = pz[c];
      float sp  = x*x + y*y + z*z;
      float dot = qx*x + qy*y + qz*z;
      float d2  = (sq + sp) - 2.0f * dot;
      if (d2 <= Tm) {
        int pos = atomicAdd(&cnt[ql], 1);
        if (pos < 24) { dbuf[ql][pos] = d2; cbuf[ql][pos] = tile * KNN_TILE + c; }
      }
    }
  }
  __syncthreads();

  if (j == 0) {
    int n = cnt[ql]; if (n > 24) n = 24;
    for (int r = 0; r < NSAMPLE; ++r) {
      float bv = 3.4e38f; int bc = 0, bp = -1;
      for (int e = 0; e < n; ++e) {
        float dv = dbuf[ql][e]; int cc = cbuf[ql][e];
        if (dv < bv || (dv == bv && cc < bc)) { bv = dv; bc = cc; bp = e; }
      }
      if (bp >= 0) dbuf[ql][bp] = 3.4e38f;
      knn[qg * NSAMPLE + r] = bc;
    }
  }
}

// ---------------------------------------------------------------------------
// Gather 16 neighbor feature rows, Linear(64->128) no bias, ReLU, max over k.
// ---------------------------------------------------------------------------
__global__ __launch_bounds__(128)
void gemm_kernel(const float* __restrict__ feat, const float* __restrict__ W,
                 const int* __restrict__ knn, float* __restrict__ out)
{
  __shared__ __align__(16) float f[NSAMPLE][CFEAT];
  __shared__ int kid[NSAMPLE];
  const int tid = threadIdx.x;
  const int q = blockIdx.x;
  const int s = q >> 11;
  if (tid < NSAMPLE) kid[tid] = knn[q * NSAMPLE + tid] & 8191;
  __syncthreads();
  for (int e = tid; e < NSAMPLE * CFEAT; e += 128) {
    int k = e >> 6, c = e & 63;
    f[k][c] = feat[(size_t)(s * SEG_N + kid[k]) * CFEAT + c];
  }
  float4 w[16];
  const float4* Wrow = (const float4*)(W + (size_t)tid * CFEAT);
  #pragma unroll
  for (int c4 = 0; c4 < 16; ++c4) w[c4] = Wrow[c4];
  __syncthreads();

  float m = -3.4e38f;
  #pragma unroll
  for (int k = 0; k < NSAMPLE; ++k) {
    float acc = 0.f;
    const float4* frow = (const float4*)&f[k][0];
    #pragma unroll
    for (int c4 = 0; c4 < 16; ++c4) {
      float4 fv = frow[c4];
      acc += fv.x * w[c4].x + fv.y * w[c4].y + fv.z * w[c4].z + fv.w * w[c4].w;
    }
    m = fmaxf(m, acc);
  }
  out[OUT_FEAT + (size_t)q * COUT + tid] = fmaxf(m, 0.f);
}

// ---------------------------------------------------------------------------
extern "C" void kernel_launch(void* const* d_in, const int* in_sizes, int n_in,
                              void* d_out, int out_size, void* d_ws, size_t ws_size,
                              hipStream_t stream)
{
  const float* xyz  = (const float*)d_in[0];
  const float* feat = (const float*)d_in[1];
  // d_in[2] = offset (segment sizes fixed by the problem)
  const float* vel  = (const float*)d_in[3];
  const float* W    = (const float*)d_in[4];
  float* out = (float*)d_out;
  char*  ws  = (char*)d_ws;
  u64* cand    = (u64*)(ws + WS_CAND);
  int* fps_idx = (int*)(ws + WS_FPS);
  int* knn     = (int*)(ws + WS_KNN);

  // step tags repeat across graph replays -> slots must start clean
  hipMemsetAsync(cand, 0, 512, stream);

  fps_kernel<<<NSEG * FPS_WGS_PER_SEG, FPS_THREADS, 0, stream>>>(
      xyz, feat, cand, fps_idx);
  gather_kernel<<<M_TOTAL / 256, 256, 0, stream>>>(xyz, vel, fps_idx, out);
  knn_kernel<<<M_TOTAL / 16, 256, 0, stream>>>(xyz, out, knn);
  gemm_kernel<<<M_TOTAL, 128, 0, stream>>>(feat, W, knn, out);
}